// Round 3
// baseline (186.512 us; speedup 1.0000x reference)
//
#include <hip/hip_runtime.h>
#include <cstddef>

// ---------------------------------------------------------------------------
// JPEG blockwise 8x8 DCT + quantization.
//   image:          [16, 1, 1024, 1024] fp32
//   quality_factor: [16] fp32
//   out:            [16, 64, 128, 128] fp32, channel c = u*8+v
//
// R3: 2 threads per 8x8 block (each computes 4 u-rows, 32 accumulators).
//  - grid 2048 WGs (8 waves/SIMD vs 4) to hide HBM latency
//  - butterfly row-DCT (8 add + 32 fma vs 64 fma)
//  - -128 centering folded into a single DC correction (D[0][0] -= 1024)
//  - nontemporal stores (write-once output, keep L2 for input re-reads)
// Roofline: 64 MB in + 64 MB out => ~20 us at 6.3 TB/s.
// ---------------------------------------------------------------------------

// 0.5*cos(m*pi/16) for m = 0..31 (full period; high-precision literals).
static constexpr float COSTAB[32] = {
     0.50000000000000000f,  0.49039264020161522f,  0.46193976625564337f,
     0.41573480615127262f,  0.35355339059327373f,  0.27778511650980114f,
     0.19134171618254492f,  0.09754516100806417f,  0.00000000000000000f,
    -0.09754516100806417f, -0.19134171618254492f, -0.27778511650980114f,
    -0.35355339059327373f, -0.41573480615127262f, -0.46193976625564337f,
    -0.49039264020161522f, -0.50000000000000000f, -0.49039264020161522f,
    -0.46193976625564337f, -0.41573480615127262f, -0.35355339059327373f,
    -0.27778511650980114f, -0.19134171618254492f, -0.09754516100806417f,
     0.00000000000000000f,  0.09754516100806417f,  0.19134171618254492f,
     0.27778511650980114f,  0.35355339059327373f,  0.41573480615127262f,
     0.46193976625564337f,  0.49039264020161522f,
};

// C[k][n] = a_k * cos(pi*k*(2n+1)/16); a_0 = 1/(2*sqrt(2)), a_k = 1/2.
// Symmetry used below: C[k][7-n] = (-1)^k * C[k][n].
__device__ __host__ __forceinline__ constexpr float dctC(int k, int n) {
    return (k == 0) ? 0.35355339059327373f
                    : COSTAB[(k * (2 * n + 1)) & 31];
}

static constexpr float LUMQ[64] = {
    16, 11, 10, 16, 24, 40, 51, 61,
    12, 12, 14, 19, 26, 58, 60, 55,
    14, 13, 16, 24, 40, 57, 69, 56,
    14, 17, 22, 29, 51, 87, 80, 62,
    18, 22, 37, 56, 68, 109, 103, 77,
    24, 36, 55, 64, 81, 104, 113, 92,
    49, 64, 78, 87, 103, 121, 120, 101,
    72, 92, 95, 98, 112, 100, 103, 99,
};

// Reference uses Q = LUMQ/100, so 1/Q = 100/LUMQ (compile-time constant).
__device__ __host__ __forceinline__ constexpr float invQ(int u, int v) {
    return 100.0f / LUMQ[u * 8 + v];
}

__global__ __launch_bounds__(256, 6) void jpeg_dct_quant_kernel(
    const float* __restrict__ img,   // [16,1,1024,1024]
    const float* __restrict__ qfv,   // [16]
    float* __restrict__ out)         // [16,64,128,128]
{
    // One workgroup = one full block-row (128 blocks along j), 2 threads/block.
    // tid 0..127: half 0 (u = 0..3) of blocks j = tid
    // tid 128..255: half 1 (u = 4..7) of blocks j = tid-128
    // => wave = 64 consecutive j, one half: stores are 256 B dense per instr.
    const int tid  = threadIdx.x;
    const int half = tid >> 7;           // wave-uniform
    const int j    = tid & 127;
    const int row  = blockIdx.x;         // 0..2047 = b*128 + i
    const int b    = row >> 7;
    const int i    = row & 127;
    const int u0   = half * 4;

    const float* src = img + ((size_t)b << 20) + (size_t)(i * 8) * 1024 + j * 8;

    float acc[4][8];
    #pragma unroll
    for (int uu = 0; uu < 4; ++uu)
        #pragma unroll
        for (int v = 0; v < 8; ++v)
            acc[uu][v] = 0.0f;

    #pragma unroll
    for (int n = 0; n < 8; ++n) {
        const float4 r0 = *reinterpret_cast<const float4*>(src + (size_t)n * 1024);
        const float4 r1 = *reinterpret_cast<const float4*>(src + (size_t)n * 1024 + 4);
        // Butterfly: s_m = x[m]+x[7-m], d_m = x[m]-x[7-m]  (raw pixels; the
        // -128 centering only affects the DC term, corrected once below).
        const float s0 = r0.x + r1.w, s1 = r0.y + r1.z;
        const float s2 = r0.z + r1.y, s3 = r0.w + r1.x;
        const float d0 = r0.x - r1.w, d1 = r0.y - r1.z;
        const float d2 = r0.z - r1.y, d3 = r0.w - r1.x;

        // Row DCT: even v from sums, odd v from diffs (4 fma each).
        float y[8];
        #pragma unroll
        for (int v = 0; v < 8; v += 2)
            y[v] = s0 * dctC(v, 0) + s1 * dctC(v, 1)
                 + s2 * dctC(v, 2) + s3 * dctC(v, 3);
        #pragma unroll
        for (int v = 1; v < 8; v += 2)
            y[v] = d0 * dctC(v, 0) + d1 * dctC(v, 1)
                 + d2 * dctC(v, 2) + d3 * dctC(v, 3);

        // Column accumulate for this half's 4 u-rows.
        #pragma unroll
        for (int uu = 0; uu < 4; ++uu) {
            const float cu = dctC(u0 + uu, n);
            #pragma unroll
            for (int v = 0; v < 8; ++v)
                acc[uu][v] += cu * y[v];
        }
    }

    // DC correction for the skipped -128 centering: D[0][0] -= 128*64/8.
    if (half == 0) acc[0][0] -= 1024.0f;   // wave-uniform branch

    const float qf = qfv[b];
    const float factor = (qf < 50.0f) ? (5000.0f / qf) : (200.0f - 2.0f * qf);
    const float invf = 1.0f / factor;

    float* dst = out + ((size_t)b << 20) + (size_t)i * 128 + j;
    #pragma unroll
    for (int uu = 0; uu < 4; ++uu) {
        const int u = u0 + uu;
        #pragma unroll
        for (int v = 0; v < 8; ++v) {
            const float val = acc[uu][v] * (invf * invQ(u, v));
            __builtin_nontemporal_store(val, dst + (size_t)(u * 8 + v) * 16384);
        }
    }
}

extern "C" void kernel_launch(void* const* d_in, const int* in_sizes, int n_in,
                              void* d_out, int out_size, void* d_ws, size_t ws_size,
                              hipStream_t stream) {
    const float* img = (const float*)d_in[0];   // 16*1024*1024 fp32
    const float* qfv = (const float*)d_in[1];   // 16 fp32
    float* out = (float*)d_out;                 // 16*64*128*128 fp32

    // 2048 block-rows (16 b x 128 i), one WG each; 2 threads per 8x8 block.
    jpeg_dct_quant_kernel<<<2048, 256, 0, stream>>>(img, qfv, out);
}

// Round 4
// 111.238 us; speedup vs baseline: 1.6767x; 1.6767x over previous
//
#include <hip/hip_runtime.h>
#include <cstddef>

// ---------------------------------------------------------------------------
// JPEG blockwise 8x8 DCT + quantization.
//   image:          [16, 1, 1024, 1024] fp32
//   quality_factor: [16] fp32
//   out:            [16, 64, 128, 128] fp32, channel c = u*8+v
//
// R4: revert R3's nt-store + 2-thread split (WRITE_SIZE 3.2x amplification,
// FETCH 1.67x from duplicate reads). Back to R2's clean memory pattern
// (1 thread/block, normal stores, each line touched once) + AAN scaled
// fast DCT (jfdctflt flowgraph): 576 VALU instr/block vs ~900.
// AAN output scales 1/(8*aans[u]*aans[v]) folded into the quant table;
// -128 centering folded into a single raw-DC correction (-8192).
// Roofline: 64 MB in + 64 MB out => ~20 us at 6.3 TB/s; VALU ~11 us.
// ---------------------------------------------------------------------------

static constexpr double LUMQ[64] = {
    16, 11, 10, 16, 24, 40, 51, 61,
    12, 12, 14, 19, 26, 58, 60, 55,
    14, 13, 16, 24, 40, 57, 69, 56,
    14, 17, 22, 29, 51, 87, 80, 62,
    18, 22, 37, 56, 68, 109, 103, 77,
    24, 36, 55, 64, 81, 104, 113, 92,
    49, 64, 78, 87, 103, 121, 120, 101,
    72, 92, 95, 98, 112, 100, 103, 99,
};

// AAN per-coefficient scale: sqrt(2)*cos(k*pi/16), k=1..7; 1.0 for k=0.
static constexpr double AANS[8] = {
    1.0, 1.3870398453221475, 1.3065629648763766, 1.1758756024193588,
    1.0, 0.7856949583871022, 0.5411961001461970, 0.2758993792829430,
};

// Reference divides by Q = LUMQ/100; AAN raw 2D output is
// 8*aans[u]*aans[v] times the orthonormal DCT. Fold both (compile-time).
__device__ __host__ __forceinline__ constexpr float outScale(int u, int v) {
    return (float)(100.0 / (LUMQ[u * 8 + v] * 8.0 * AANS[u] * AANS[v]));
}

// AAN 8-point scaled forward DCT (jfdctflt.c flowgraph).
// In-place; output k is the true orthonormal DCT * sqrt(8) * aans[k].
__device__ __forceinline__ void aan_dct8(float& x0, float& x1, float& x2,
                                         float& x3, float& x4, float& x5,
                                         float& x6, float& x7) {
    const float t0 = x0 + x7, t7 = x0 - x7;
    const float t1 = x1 + x6, t6 = x1 - x6;
    const float t2 = x2 + x5, t5 = x2 - x5;
    const float t3 = x3 + x4, t4 = x3 - x4;

    // Even part
    float t10 = t0 + t3;
    const float t13 = t0 - t3;
    const float t11 = t1 + t2;
    const float t12 = t1 - t2;
    x0 = t10 + t11;
    x4 = t10 - t11;
    const float z1 = (t12 + t13) * 0.70710678118654752f;
    x2 = t13 + z1;
    x6 = t13 - z1;

    // Odd part
    t10 = t4 + t5;
    const float u11 = t5 + t6;
    const float u12 = t6 + t7;
    const float z5 = (t10 - u12) * 0.38268343236508977f;
    const float z2 = 0.54119610014619698f * t10 + z5;
    const float z4 = 1.30656296487637653f * u12 + z5;
    const float z3 = u11 * 0.70710678118654752f;
    const float z11 = t7 + z3;
    const float z13 = t7 - z3;
    x5 = z13 + z2;
    x3 = z13 - z2;
    x1 = z11 + z4;
    x7 = z11 - z4;
}

__global__ __launch_bounds__(256) void jpeg_dct_quant_kernel(
    const float* __restrict__ img,   // [16,1,1024,1024]
    const float* __restrict__ qfv,   // [16]
    float* __restrict__ out)         // [16,64,128,128]
{
    const int bid = blockIdx.x * 256 + threadIdx.x;   // global 8x8-block id
    const int j = bid & 127;           // block col
    const int i = (bid >> 7) & 127;    // block row
    const int b = bid >> 14;           // batch

    const float* src = img + ((size_t)b << 20) + (size_t)(i * 8) * 1024 + j * 8;

    // Load the full 8x8 block first (MLP = 16 outstanding float4 loads).
    float m[8][8];
    #pragma unroll
    for (int n = 0; n < 8; ++n) {
        const float4 r0 = *reinterpret_cast<const float4*>(src + (size_t)n * 1024);
        const float4 r1 = *reinterpret_cast<const float4*>(src + (size_t)n * 1024 + 4);
        m[n][0] = r0.x; m[n][1] = r0.y; m[n][2] = r0.z; m[n][3] = r0.w;
        m[n][4] = r1.x; m[n][5] = r1.y; m[n][6] = r1.z; m[n][7] = r1.w;
    }

    // Row pass (along columns within each row).
    #pragma unroll
    for (int n = 0; n < 8; ++n)
        aan_dct8(m[n][0], m[n][1], m[n][2], m[n][3],
                 m[n][4], m[n][5], m[n][6], m[n][7]);

    // Column pass.
    #pragma unroll
    for (int v = 0; v < 8; ++v)
        aan_dct8(m[0][v], m[1][v], m[2][v], m[3][v],
                 m[4][v], m[5][v], m[6][v], m[7][v]);

    // -128 centering only affects the raw DC term: 128*64 = 8192.
    m[0][0] -= 8192.0f;

    const float qf = qfv[b];
    const float factor = (qf < 50.0f) ? (5000.0f / qf) : (200.0f - 2.0f * qf);
    const float invf = 1.0f / factor;

    // Stores: lane = consecutive j => each wave store instr is 256 B dense.
    float* dst = out + ((size_t)b << 20) + (size_t)i * 128 + j;
    #pragma unroll
    for (int u = 0; u < 8; ++u)
        #pragma unroll
        for (int v = 0; v < 8; ++v)
            dst[(size_t)(u * 8 + v) * 16384] = m[u][v] * (invf * outScale(u, v));
}

extern "C" void kernel_launch(void* const* d_in, const int* in_sizes, int n_in,
                              void* d_out, int out_size, void* d_ws, size_t ws_size,
                              hipStream_t stream) {
    const float* img = (const float*)d_in[0];   // 16*1024*1024 fp32
    const float* qfv = (const float*)d_in[1];   // 16 fp32
    float* out = (float*)d_out;                 // 16*64*128*128 fp32

    // 16*128*128 = 262144 blocks, one thread each; 256 threads/WG -> 1024 WGs.
    jpeg_dct_quant_kernel<<<1024, 256, 0, stream>>>(img, qfv, out);
}